// Round 7
// baseline (8367.264 us; speedup 1.0000x reference)
//
#include <hip/hip_runtime.h>
#include <hip/hip_bf16.h>

// ForecastNetSimple: B=128, T=512, I=8, H=512, W=96
// Round 7: round-6 MFMA structure with two fixes:
//  (1) BUG FIX: WfcL staging used `if (tid < 513)` with a 256-thread block ->
//      WfcL[256..512] was uninitialized LDS; every decoder pred was garbage.
//      Now a strided loop covers all 513 entries.
//  (2) h exchanged as a THREE-part bf16 split (hh+hl+hl2, residual ~2^-27|h|,
//      i.e. effectively exact fp32): the LSTM recurrence amplifies per-step
//      noise ~10^3-10^4x over 512 steps; the 2-way split's 2^-18 error risked
//      the 0.01 threshold. 3 MFMAs per (kb,tile) instead of 2.
// 64 blocks x 256 threads (4 waves), block = 16 h-rows x 64 batch cols.
// mfma_f32_16x16x32_bf16; A-frags prepacked+staged in LDS; encoder x-term is
// a 17th K-block. Cross-block h/flags via relaxed AGENT-scope atomics.

typedef __attribute__((ext_vector_type(8))) short short8;
typedef __attribute__((ext_vector_type(4))) float f32x4;

#define FS 32  // dwords between flags (128 B)

// ---------- dtype helpers ----------
__device__ __forceinline__ float ldf(const void* p, size_t i, int isbf) {
  if (isbf) return __uint_as_float((unsigned)((const unsigned short*)p)[i] << 16);
  return ((const float*)p)[i];
}
__device__ __forceinline__ unsigned short f2bf(float x) {  // RNE
  unsigned u = __float_as_uint(x);
  return (unsigned short)((u + 0x7fff + ((u >> 16) & 1)) >> 16);
}
__device__ __forceinline__ unsigned short ldbf(const void* p, size_t i, int isbf) {
  if (isbf) return ((const unsigned short*)p)[i];
  return f2bf(((const float*)p)[i]);
}
__device__ __forceinline__ float bf2f(short s) {
  return __uint_as_float((unsigned)(unsigned short)s << 16);
}

// ---------- coherent helpers ----------
__device__ __forceinline__ unsigned ld_flag(const unsigned* p) {
  return __hip_atomic_load(p, __ATOMIC_RELAXED, __HIP_MEMORY_SCOPE_AGENT);
}
__device__ __forceinline__ void st_flag(unsigned* p, unsigned v) {
  __hip_atomic_store(p, v, __ATOMIC_RELAXED, __HIP_MEMORY_SCOPE_AGENT);
}
__device__ __forceinline__ unsigned long long ld_h64(const unsigned long long* p) {
  return __hip_atomic_load(p, __ATOMIC_RELAXED, __HIP_MEMORY_SCOPE_AGENT);
}
__device__ __forceinline__ void st_h64(unsigned long long* p, unsigned long long v) {
  __hip_atomic_store(p, v, __ATOMIC_RELAXED, __HIP_MEMORY_SCOPE_AGENT);
}
__device__ __forceinline__ short8 mk8(unsigned long long a, unsigned long long b) {
  union { unsigned long long q[2]; short8 v; } u; u.q[0] = a; u.q[1] = b; return u.v;
}

// ---------- probe: bf16 vs fp32 input buffers ----------
__global__ void k_probe(const unsigned int* __restrict__ src_raw, int* __restrict__ flag) {
  __shared__ int cnt;
  if (threadIdx.x == 0) cnt = 0;
  __syncthreads();
  int c = 0;
  for (int i = threadIdx.x; i < 512; i += 256) {
    unsigned v = src_raw[i];
    float f = __uint_as_float((v & 0xffffu) << 16);
    float a = fabsf(f);
    if (a > 0.00390625f && a < 4.0f) c++;
  }
  atomicAdd(&cnt, c);
  __syncthreads();
  if (threadIdx.x == 0) *flag = (cnt > 256) ? 1 : 0;
}

// ---------- prepack A fragments ----------
// enc: bidp in [0,2176): hb=bidp/68, t=(bidp%68)/17, kb=bidp%17  (kb 16 = x-block)
// dec: bidp-2176 in [0,2048): hb=/64, t=(%64)/16, kb=%16
__global__ void k_prep_frags(const void* __restrict__ Whh_e, const void* __restrict__ Whh_d,
                             const void* __restrict__ Wih_e,
                             short* __restrict__ AEnc, short* __restrict__ ADec,
                             const int* __restrict__ flag) {
  const int isbf = *flag;
  const int lane = threadIdx.x;            // 64 threads
  const int m = lane & 15, qd = lane >> 4;
  int bidp = blockIdx.x;
  if (bidp < 2176) {
    const int hb = bidp / 68, rem = bidp % 68, t = rem / 17, kb = rem % 17;
    const int row = t * 512 + hb * 16 + m;
    short v[8];
#pragma unroll
    for (int j = 0; j < 8; ++j) {
      if (kb < 16) {
        int k = kb * 32 + qd * 8 + j;
        v[j] = (short)ldbf(Whh_e, (size_t)row * 512 + k, isbf);
      } else {
        v[j] = (qd == 0) ? (short)ldbf(Wih_e, (size_t)row * 8 + j, isbf) : (short)0;
      }
    }
    short* dst = AEnc + ((size_t)bidp * 64 + lane) * 8;
#pragma unroll
    for (int j = 0; j < 8; ++j) dst[j] = v[j];
  } else {
    bidp -= 2176;
    const int hb = bidp / 64, rem = bidp % 64, t = rem / 16, kb = rem % 16;
    const int row = t * 512 + hb * 16 + m;
    short* dst = ADec + ((size_t)bidp * 64 + lane) * 8;
#pragma unroll
    for (int j = 0; j < 8; ++j) {
      int k = kb * 32 + qd * 8 + j;
      dst[j] = (short)ldbf(Whh_d, (size_t)row * 512 + k, isbf);
    }
  }
}

// ---------- prepack encoder x B-frags: XF[t][col][8] bf16 ----------
__global__ void k_prep_xf(const void* __restrict__ src, unsigned short* __restrict__ XF,
                          const int* __restrict__ flag) {
  const int isbf = *flag;
  int idx = blockIdx.x * 256 + threadIdx.x;        // < 524288
  int t = idx >> 10, rem = idx & 1023, col = rem >> 3, i = rem & 7;
  XF[idx] = ldbf(src, ((size_t)col * 512 + t) * 8 + i, isbf);
}

// ---------- small prep: biases, folded decoder input, Wfc, flags ----------
__global__ void k_prep_small(const void* __restrict__ bih_e, const void* __restrict__ bhh_e,
                             const void* __restrict__ bih_d, const void* __restrict__ bhh_d,
                             const void* __restrict__ Wih_d, const void* __restrict__ Wp,
                             const void* __restrict__ bp, const void* __restrict__ Wfc,
                             const void* __restrict__ bfc,
                             float* __restrict__ bE, float* __restrict__ uD,
                             float* __restrict__ bD, float* __restrict__ WfcF,
                             unsigned* __restrict__ arr, const int* __restrict__ flag) {
  const int isbf = *flag;
  const int b = blockIdx.x;
  if (b < 8) {
    int g = b * 256 + threadIdx.x;
    bE[g] = ldf(bih_e, g, isbf) + ldf(bhh_e, g, isbf);
    float u = 0.f, w0 = 0.f;
    for (int i = 0; i < 8; ++i) {
      float wv = ldf(Wih_d, (size_t)g * 8 + i, isbf);
      u  += wv * ldf(Wp, i, isbf);
      w0 += wv * ldf(bp, i, isbf);
    }
    uD[g] = u;
    bD[g] = ldf(bih_d, g, isbf) + ldf(bhh_d, g, isbf) + w0;
  } else if (b == 8) {
    for (int k = threadIdx.x; k < 513; k += 256)
      WfcF[k] = (k < 512) ? ldf(Wfc, k, isbf) : ldf(bfc, 0, isbf);
  } else {
    for (int i = threadIdx.x; i < 64 * FS; i += 256) arr[i] = 0u;
  }
}

// ---------- math ----------
__device__ __forceinline__ float sigm(float x) { return 1.0f / (1.0f + __expf(-x)); }
__device__ __forceinline__ float tanh_(float x) {
  float ax = fabsf(x);
  float e = __expf(-2.0f * ax);
  float t = (1.0f - e) / (1.0f + e);
  return copysignf(t, x);
}

// ---------- main persistent recurrent kernel ----------
__global__ __launch_bounds__(256, 1) void k_rnn(
    const short* __restrict__ AEnc, const short* __restrict__ ADec,
    const unsigned short* __restrict__ XF,
    const float* __restrict__ bE, const float* __restrict__ uD,
    const float* __restrict__ bD, const float* __restrict__ WfcF,
    unsigned long long* __restrict__ hHiA, unsigned long long* __restrict__ hLoA,
    unsigned long long* __restrict__ hL2A,
    unsigned long long* __restrict__ hHiB, unsigned long long* __restrict__ hLoB,
    unsigned long long* __restrict__ hL2B,
    void* __restrict__ outp, const int* __restrict__ flag,
    unsigned* __restrict__ arr, const void* __restrict__ src) {
  const int bid  = (int)blockIdx.x;       // 64 blocks
  const int hb   = bid >> 1;              // h-rows hb*16 .. +16
  const int half = bid & 1;
  const int tid  = (int)threadIdx.x;
  const int lane = tid & 63;
  const int w    = __builtin_amdgcn_readfirstlane(tid >> 6);  // col-tile 0..3
  const int n    = lane & 15, q = lane >> 4;
  const int col  = half * 64 + w * 16 + n;

  __shared__ short AeL[4 * 17 * 512];     // 69632 B
  __shared__ short AdL[4 * 16 * 512];     // 65536 B
  __shared__ float WfcL[520];
  __shared__ float bEL[64], uDL[64], bDL[64];
  __shared__ unsigned relstep;

  // ---- one-time staging ----
  {
    const float4* s1 = (const float4*)(AEnc + (size_t)hb * 34816);
    float4* d1 = (float4*)AeL;
    for (int i = tid; i < 4352; i += 256) d1[i] = s1[i];
    const float4* s2 = (const float4*)(ADec + (size_t)hb * 32768);
    float4* d2 = (float4*)AdL;
    for (int i = tid; i < 4096; i += 256) d2[i] = s2[i];
    for (int k = tid; k < 513; k += 256) WfcL[k] = WfcF[k];   // FIXED: full coverage
    if (tid < 64) {
      int t = tid >> 4, m = tid & 15;
      int g = t * 512 + hb * 16 + m;
      bEL[tid] = bE[g]; uDL[tid] = uD[g]; bDL[tid] = bD[g];
    }
    if (tid == 0) relstep = 0u;
  }
  const int isbf = *flag;
  const unsigned* pf = arr + (size_t)(((lane & 31) * 2 + half) * FS);
  unsigned* myflag = arr + (size_t)bid * FS;
  __syncthreads();

  const size_t bbase = (size_t)col * 128 + q * 2;        // u64 idx of B chunk
  const size_t sbase = (size_t)col * 128 + hb * 4 + q;   // u64 idx of h store
  float cst[4] = {0.f, 0.f, 0.f, 0.f};

#define WAIT(nn)                                                              \
  do {                                                                        \
    unsigned _n = (unsigned)(nn);                                             \
    if (w == 0) {                                                             \
      while (!__all((int)(ld_flag(pf) >= _n))) __builtin_amdgcn_s_sleep(1);   \
      asm volatile("" ::: "memory");                                          \
      if (lane == 0)                                                          \
        __hip_atomic_store(&relstep, _n, __ATOMIC_RELEASE,                    \
                           __HIP_MEMORY_SCOPE_WORKGROUP);                     \
    } else {                                                                  \
      while (__hip_atomic_load(&relstep, __ATOMIC_ACQUIRE,                    \
                               __HIP_MEMORY_SCOPE_WORKGROUP) < _n)            \
        __builtin_amdgcn_s_sleep(1);                                          \
    }                                                                         \
  } while (0)

  // ================= encoder: 512 steps =================
  for (int t = 0; t < 512; ++t) {
    const unsigned long long* pHi = (t & 1) ? hHiB : hHiA;
    const unsigned long long* pLo = (t & 1) ? hLoB : hLoA;
    const unsigned long long* pL2 = (t & 1) ? hL2B : hL2A;
    unsigned long long* sHi = (t & 1) ? hHiA : hHiB;
    unsigned long long* sLo = (t & 1) ? hLoA : hLoB;
    unsigned long long* sL2 = (t & 1) ? hL2A : hL2B;
    f32x4 acc[4] = {{0.f,0.f,0.f,0.f},{0.f,0.f,0.f,0.f},{0.f,0.f,0.f,0.f},{0.f,0.f,0.f,0.f}};
    short8 xb = mk8(0ull, 0ull);
    if (q == 0) xb = *(const short8*)((const short*)XF + ((size_t)t * 128 + col) * 8);

    if (t > 0) {
      WAIT(t);
      unsigned long long ha = ld_h64(pHi + bbase), hbq = ld_h64(pHi + bbase + 1);
      unsigned long long la = ld_h64(pLo + bbase), lb  = ld_h64(pLo + bbase + 1);
      unsigned long long ma = ld_h64(pL2 + bbase), mb  = ld_h64(pL2 + bbase + 1);
      for (int kb = 0; kb < 16; ++kb) {
        size_t o = bbase + (size_t)((kb < 15) ? (kb + 1) : kb) * 8;  // clamped prefetch
        unsigned long long nha = ld_h64(pHi + o), nhb = ld_h64(pHi + o + 1);
        unsigned long long nla = ld_h64(pLo + o), nlb = ld_h64(pLo + o + 1);
        unsigned long long nma = ld_h64(pL2 + o), nmb = ld_h64(pL2 + o + 1);
        short8 b0 = mk8(ha, hbq), b1 = mk8(la, lb), b2 = mk8(ma, mb);
#pragma unroll
        for (int tt = 0; tt < 4; ++tt) {
          short8 a = *(const short8*)(AeL + ((size_t)(tt * 17 + kb) * 64 + lane) * 8);
          acc[tt] = __builtin_amdgcn_mfma_f32_16x16x32_bf16(a, b0, acc[tt], 0, 0, 0);
          acc[tt] = __builtin_amdgcn_mfma_f32_16x16x32_bf16(a, b1, acc[tt], 0, 0, 0);
          acc[tt] = __builtin_amdgcn_mfma_f32_16x16x32_bf16(a, b2, acc[tt], 0, 0, 0);
        }
        ha = nha; hbq = nhb; la = nla; lb = nlb; ma = nma; mb = nmb;
      }
    }
#pragma unroll
    for (int tt = 0; tt < 4; ++tt) {   // x-term K-block
      short8 a = *(const short8*)(AeL + ((size_t)(tt * 17 + 16) * 64 + lane) * 8);
      acc[tt] = __builtin_amdgcn_mfma_f32_16x16x32_bf16(a, xb, acc[tt], 0, 0, 0);
    }
    // combine (intra-thread: rows q*4+r, col)
    unsigned long long packH = 0ull, packL = 0ull, pack2 = 0ull;
#pragma unroll
    for (int r = 0; r < 4; ++r) {
      int m = q * 4 + r;
      float gi = acc[0][r] + bEL[m];
      float gf = acc[1][r] + bEL[16 + m];
      float gg = acc[2][r] + bEL[32 + m];
      float go = acc[3][r] + bEL[48 + m];
      cst[r] = sigm(gf) * cst[r] + sigm(gi) * tanh_(gg);
      float h = sigm(go) * tanh_(cst[r]);
      unsigned short hh = f2bf(h);
      float r1 = h - bf2f((short)hh);
      unsigned short hl = f2bf(r1);
      unsigned short hl2 = f2bf(r1 - bf2f((short)hl));
      packH |= (unsigned long long)hh  << (16 * r);
      packL |= (unsigned long long)hl  << (16 * r);
      pack2 |= (unsigned long long)hl2 << (16 * r);
    }
    st_h64(sHi + sbase, packH);
    st_h64(sLo + sbase, packL);
    st_h64(sL2 + sbase, pack2);
    asm volatile("s_waitcnt vmcnt(0)" ::: "memory");
    __syncthreads();
    if (tid == 0) st_flag(myflag, (unsigned)(t + 1));
  }

  // ================= decoder: 96 steps =================
  for (int d = 0; d < 96; ++d) {
    const int nn = 512 + d;
    const unsigned long long* pHi = (nn & 1) ? hHiB : hHiA;
    const unsigned long long* pLo = (nn & 1) ? hLoB : hLoA;
    const unsigned long long* pL2 = (nn & 1) ? hL2B : hL2A;
    unsigned long long* sHi = (nn & 1) ? hHiA : hHiB;
    unsigned long long* sLo = (nn & 1) ? hLoA : hLoB;
    unsigned long long* sL2 = (nn & 1) ? hL2A : hL2B;
    f32x4 acc[4] = {{0.f,0.f,0.f,0.f},{0.f,0.f,0.f,0.f},{0.f,0.f,0.f,0.f},{0.f,0.f,0.f,0.f}};
    float pdot = 0.f;
    WAIT(nn);
    unsigned long long ha = ld_h64(pHi + bbase), hbq = ld_h64(pHi + bbase + 1);
    unsigned long long la = ld_h64(pLo + bbase), lb  = ld_h64(pLo + bbase + 1);
    unsigned long long ma = ld_h64(pL2 + bbase), mb  = ld_h64(pL2 + bbase + 1);
    for (int kb = 0; kb < 16; ++kb) {
      size_t o = bbase + (size_t)((kb < 15) ? (kb + 1) : kb) * 8;
      unsigned long long nha = ld_h64(pHi + o), nhb = ld_h64(pHi + o + 1);
      unsigned long long nla = ld_h64(pLo + o), nlb = ld_h64(pLo + o + 1);
      unsigned long long nma = ld_h64(pL2 + o), nmb = ld_h64(pL2 + o + 1);
      short8 b0 = mk8(ha, hbq), b1 = mk8(la, lb), b2 = mk8(ma, mb);
#pragma unroll
      for (int tt = 0; tt < 4; ++tt) {
        short8 a = *(const short8*)(AdL + ((size_t)(tt * 16 + kb) * 64 + lane) * 8);
        acc[tt] = __builtin_amdgcn_mfma_f32_16x16x32_bf16(a, b0, acc[tt], 0, 0, 0);
        acc[tt] = __builtin_amdgcn_mfma_f32_16x16x32_bf16(a, b1, acc[tt], 0, 0, 0);
        acc[tt] = __builtin_amdgcn_mfma_f32_16x16x32_bf16(a, b2, acc[tt], 0, 0, 0);
      }
#pragma unroll
      for (int j = 0; j < 8; ++j)   // Wfc dot on this lane's k-slice
        pdot += WfcL[kb * 32 + q * 8 + j] *
                (bf2f(b0[j]) + bf2f(b1[j]) + bf2f(b2[j]));
      ha = nha; hbq = nhb; la = nla; lb = nlb; ma = nma; mb = nmb;
    }
    pdot += __shfl_xor(pdot, 16);
    pdot += __shfl_xor(pdot, 32);
    float pr = sigm(pdot + WfcL[512]);              // pred from h_{512+d} = pred_{d-1}
    float xin = (d == 0) ? ldf(src, (size_t)col * 4096 + 4088, isbf) : pr;
    if (hb == 0 && q == 0 && d > 0) {
      int oi = col * 96 + (d - 1);
      if (isbf) ((unsigned short*)outp)[oi] = f2bf(pr);
      else      ((float*)outp)[oi] = pr;
    }
    unsigned long long packH = 0ull, packL = 0ull, pack2 = 0ull;
#pragma unroll
    for (int r = 0; r < 4; ++r) {
      int m = q * 4 + r;
      float gi = acc[0][r] + xin * uDL[m]      + bDL[m];
      float gf = acc[1][r] + xin * uDL[16 + m] + bDL[16 + m];
      float gg = acc[2][r] + xin * uDL[32 + m] + bDL[32 + m];
      float go = acc[3][r] + xin * uDL[48 + m] + bDL[48 + m];
      cst[r] = sigm(gf) * cst[r] + sigm(gi) * tanh_(gg);
      float h = sigm(go) * tanh_(cst[r]);
      unsigned short hh = f2bf(h);
      float r1 = h - bf2f((short)hh);
      unsigned short hl = f2bf(r1);
      unsigned short hl2 = f2bf(r1 - bf2f((short)hl));
      packH |= (unsigned long long)hh  << (16 * r);
      packL |= (unsigned long long)hl  << (16 * r);
      pack2 |= (unsigned long long)hl2 << (16 * r);
    }
    st_h64(sHi + sbase, packH);
    st_h64(sLo + sbase, packL);
    st_h64(sL2 + sbase, pack2);
    asm volatile("s_waitcnt vmcnt(0)" ::: "memory");
    __syncthreads();
    if (tid == 0) st_flag(myflag, (unsigned)(nn + 1));
  }

  // ================= epilogue: pred_95 from h_608 (buf A) =================
  if (hb == 0) {
    WAIT(608u);
    float pdot = 0.f;
    for (int kb = 0; kb < 16; ++kb) {
      size_t o = bbase + (size_t)kb * 8;
      short8 b0 = mk8(ld_h64(hHiA + o), ld_h64(hHiA + o + 1));
      short8 b1 = mk8(ld_h64(hLoA + o), ld_h64(hLoA + o + 1));
      short8 b2 = mk8(ld_h64(hL2A + o), ld_h64(hL2A + o + 1));
#pragma unroll
      for (int j = 0; j < 8; ++j)
        pdot += WfcL[kb * 32 + q * 8 + j] *
                (bf2f(b0[j]) + bf2f(b1[j]) + bf2f(b2[j]));
    }
    pdot += __shfl_xor(pdot, 16);
    pdot += __shfl_xor(pdot, 32);
    if (q == 0) {
      float pr = sigm(pdot + WfcL[512]);
      int oi = col * 96 + 95;
      if (isbf) ((unsigned short*)outp)[oi] = f2bf(pr);
      else      ((float*)outp)[oi] = pr;
    }
  }
#undef WAIT
}

// ---------- host ----------
extern "C" void kernel_launch(void* const* d_in, const int* in_sizes, int n_in,
                              void* d_out, int out_size, void* d_ws, size_t ws_size,
                              hipStream_t stream) {
  (void)in_sizes; (void)n_in; (void)out_size; (void)ws_size;
  char* ws = (char*)d_ws;
  int* flag = (int*)ws;                                   // @0
  unsigned* arr = (unsigned*)(ws + 128);                  // 64*128 B = 8192
  size_t off = 8448;
  short* AEnc = (short*)(ws + off);           off += (size_t)2176 * 512 * 2;  // 2228224
  short* ADec = (short*)(ws + off);           off += (size_t)2048 * 512 * 2;  // 2097152
  unsigned short* XF = (unsigned short*)(ws + off); off += (size_t)524288 * 2; // 1048576
  unsigned long long* hHiA = (unsigned long long*)(ws + off); off += 131072;
  unsigned long long* hLoA = (unsigned long long*)(ws + off); off += 131072;
  unsigned long long* hL2A = (unsigned long long*)(ws + off); off += 131072;
  unsigned long long* hHiB = (unsigned long long*)(ws + off); off += 131072;
  unsigned long long* hLoB = (unsigned long long*)(ws + off); off += 131072;
  unsigned long long* hL2B = (unsigned long long*)(ws + off); off += 131072;
  float* bE   = (float*)(ws + off); off += 8192;
  float* uD   = (float*)(ws + off); off += 8192;
  float* bD   = (float*)(ws + off); off += 8192;
  float* WfcF = (float*)(ws + off); off += 2080;

  // inputs: 0 src, 1 Wih_e, 2 Whh_e, 3 bih_e, 4 bhh_e, 5 Wih_d, 6 Whh_d,
  //         7 bih_d, 8 bhh_d, 9 Wp, 10 bp, 11 Wfc, 12 bfc
  k_probe<<<dim3(1), dim3(256), 0, stream>>>((const unsigned int*)d_in[0], flag);
  k_prep_frags<<<dim3(4224), dim3(64), 0, stream>>>(
      d_in[2], d_in[6], d_in[1], AEnc, ADec, flag);
  k_prep_xf<<<dim3(2048), dim3(256), 0, stream>>>(d_in[0], XF, flag);
  k_prep_small<<<dim3(10), dim3(256), 0, stream>>>(
      d_in[3], d_in[4], d_in[7], d_in[8], d_in[5], d_in[9], d_in[10],
      d_in[11], d_in[12], bE, uD, bD, WfcF, arr, flag);
  k_rnn<<<dim3(64), dim3(256), 0, stream>>>(
      AEnc, ADec, XF, bE, uD, bD, WfcF, hHiA, hLoA, hL2A, hHiB, hLoB, hL2B,
      d_out, flag, arr, d_in[0]);
}

// Round 9
// 5076.829 us; speedup vs baseline: 1.6481x; 1.6481x over previous
//
#include <hip/hip_runtime.h>
#include <hip/hip_bf16.h>

// ForecastNetSimple: B=128, T=512, I=8, H=512, W=96
// Round 9: r8 structure, two fixes:
//  (1) BUG FIX: r8 issued 32 separate inline-asm global_load_dwordx4 and drained
//      vmcnt manually -> compiler could copy/spill in-flight dest registers
//      (asm "defines" them at issue, data arrives at vmcnt retire) -> sporadic
//      stale h (absmax 3.7e-2). Now ONE asm block: 32 loads w/ offset imms +
//      s_waitcnt vmcnt(0) INSIDE, outputs early-clobber (=&v). No in-flight
//      register is ever visible to the compiler.
//  (2) decoder Wfc dot reverted to the triple-bf16 sum (bit-identical to r7's
//      verified absmax-0.0 math; r8's fp32 dot was the only math delta).
// 64 blocks x 256 threads, 1 block/CU; h exchanged fp32, consumer-side exact
// 3-way bf16 RNE split; per-wave flags, no __syncthreads in the 608-step loop.

typedef __attribute__((ext_vector_type(8))) short short8;
typedef __attribute__((ext_vector_type(4))) float f32x4;

#define FS 32  // dwords between flags (128 B)

// ---------- dtype helpers ----------
__device__ __forceinline__ float ldf(const void* p, size_t i, int isbf) {
  if (isbf) return __uint_as_float((unsigned)((const unsigned short*)p)[i] << 16);
  return ((const float*)p)[i];
}
__device__ __forceinline__ unsigned short f2bf(float x) {  // RNE
  unsigned u = __float_as_uint(x);
  return (unsigned short)((u + 0x7fff + ((u >> 16) & 1)) >> 16);
}
__device__ __forceinline__ unsigned short ldbf(const void* p, size_t i, int isbf) {
  if (isbf) return ((const unsigned short*)p)[i];
  return f2bf(((const float*)p)[i]);
}
__device__ __forceinline__ float bf2f(short s) {
  return __uint_as_float((unsigned)(unsigned short)s << 16);
}

// ---------- coherent access ----------
__device__ __forceinline__ unsigned ld_flag(const unsigned* p) {
  return __hip_atomic_load(p, __ATOMIC_RELAXED, __HIP_MEMORY_SCOPE_AGENT);
}
__device__ __forceinline__ void st_flag(unsigned* p, unsigned v) {
  __hip_atomic_store(p, v, __ATOMIC_RELAXED, __HIP_MEMORY_SCOPE_AGENT);
}
__device__ __forceinline__ void st_cx4(float* p, f32x4 v) {
  asm volatile("global_store_dwordx4 %0, %1, off sc0 sc1" :: "v"(p), "v"(v) : "memory");
}
__device__ __forceinline__ void vm_drain() {
  asm volatile("s_waitcnt vmcnt(0)" ::: "memory");
}

// ---- batch h load: 32 x b128 coherent loads + internal drain (contract-safe) ----
__device__ __forceinline__ void load_h32(const float* p, f32x4 hv[32]) {
  asm volatile(
    "global_load_dwordx4 %0, %32, off sc0 sc1\n\t"
    "global_load_dwordx4 %1, %32, off offset:16 sc0 sc1\n\t"
    "global_load_dwordx4 %2, %32, off offset:128 sc0 sc1\n\t"
    "global_load_dwordx4 %3, %32, off offset:144 sc0 sc1\n\t"
    "global_load_dwordx4 %4, %32, off offset:256 sc0 sc1\n\t"
    "global_load_dwordx4 %5, %32, off offset:272 sc0 sc1\n\t"
    "global_load_dwordx4 %6, %32, off offset:384 sc0 sc1\n\t"
    "global_load_dwordx4 %7, %32, off offset:400 sc0 sc1\n\t"
    "global_load_dwordx4 %8, %32, off offset:512 sc0 sc1\n\t"
    "global_load_dwordx4 %9, %32, off offset:528 sc0 sc1\n\t"
    "global_load_dwordx4 %10, %32, off offset:640 sc0 sc1\n\t"
    "global_load_dwordx4 %11, %32, off offset:656 sc0 sc1\n\t"
    "global_load_dwordx4 %12, %32, off offset:768 sc0 sc1\n\t"
    "global_load_dwordx4 %13, %32, off offset:784 sc0 sc1\n\t"
    "global_load_dwordx4 %14, %32, off offset:896 sc0 sc1\n\t"
    "global_load_dwordx4 %15, %32, off offset:912 sc0 sc1\n\t"
    "global_load_dwordx4 %16, %32, off offset:1024 sc0 sc1\n\t"
    "global_load_dwordx4 %17, %32, off offset:1040 sc0 sc1\n\t"
    "global_load_dwordx4 %18, %32, off offset:1152 sc0 sc1\n\t"
    "global_load_dwordx4 %19, %32, off offset:1168 sc0 sc1\n\t"
    "global_load_dwordx4 %20, %32, off offset:1280 sc0 sc1\n\t"
    "global_load_dwordx4 %21, %32, off offset:1296 sc0 sc1\n\t"
    "global_load_dwordx4 %22, %32, off offset:1408 sc0 sc1\n\t"
    "global_load_dwordx4 %23, %32, off offset:1424 sc0 sc1\n\t"
    "global_load_dwordx4 %24, %32, off offset:1536 sc0 sc1\n\t"
    "global_load_dwordx4 %25, %32, off offset:1552 sc0 sc1\n\t"
    "global_load_dwordx4 %26, %32, off offset:1664 sc0 sc1\n\t"
    "global_load_dwordx4 %27, %32, off offset:1680 sc0 sc1\n\t"
    "global_load_dwordx4 %28, %32, off offset:1792 sc0 sc1\n\t"
    "global_load_dwordx4 %29, %32, off offset:1808 sc0 sc1\n\t"
    "global_load_dwordx4 %30, %32, off offset:1920 sc0 sc1\n\t"
    "global_load_dwordx4 %31, %32, off offset:1936 sc0 sc1\n\t"
    "s_waitcnt vmcnt(0)"
    : "=&v"(hv[0]),  "=&v"(hv[1]),  "=&v"(hv[2]),  "=&v"(hv[3]),
      "=&v"(hv[4]),  "=&v"(hv[5]),  "=&v"(hv[6]),  "=&v"(hv[7]),
      "=&v"(hv[8]),  "=&v"(hv[9]),  "=&v"(hv[10]), "=&v"(hv[11]),
      "=&v"(hv[12]), "=&v"(hv[13]), "=&v"(hv[14]), "=&v"(hv[15]),
      "=&v"(hv[16]), "=&v"(hv[17]), "=&v"(hv[18]), "=&v"(hv[19]),
      "=&v"(hv[20]), "=&v"(hv[21]), "=&v"(hv[22]), "=&v"(hv[23]),
      "=&v"(hv[24]), "=&v"(hv[25]), "=&v"(hv[26]), "=&v"(hv[27]),
      "=&v"(hv[28]), "=&v"(hv[29]), "=&v"(hv[30]), "=&v"(hv[31])
    : "v"(p)
    : "memory");
}

// ---------- probe: bf16 vs fp32 input buffers ----------
__global__ void k_probe(const unsigned int* __restrict__ src_raw, int* __restrict__ flag) {
  __shared__ int cnt;
  if (threadIdx.x == 0) cnt = 0;
  __syncthreads();
  int c = 0;
  for (int i = threadIdx.x; i < 512; i += 256) {
    unsigned v = src_raw[i];
    float f = __uint_as_float((v & 0xffffu) << 16);
    float a = fabsf(f);
    if (a > 0.00390625f && a < 4.0f) c++;
  }
  atomicAdd(&cnt, c);
  __syncthreads();
  if (threadIdx.x == 0) *flag = (cnt > 256) ? 1 : 0;
}

// ---------- prepack A fragments ----------
__global__ void k_prep_frags(const void* __restrict__ Whh_e, const void* __restrict__ Whh_d,
                             const void* __restrict__ Wih_e,
                             short* __restrict__ AEnc, short* __restrict__ ADec,
                             const int* __restrict__ flag) {
  const int isbf = *flag;
  const int lane = threadIdx.x;            // 64 threads
  const int m = lane & 15, qd = lane >> 4;
  int bidp = blockIdx.x;
  if (bidp < 2176) {
    const int hb = bidp / 68, rem = bidp % 68, t = rem / 17, kb = rem % 17;
    const int row = t * 512 + hb * 16 + m;
    short v[8];
#pragma unroll
    for (int j = 0; j < 8; ++j) {
      if (kb < 16) {
        int k = kb * 32 + qd * 8 + j;
        v[j] = (short)ldbf(Whh_e, (size_t)row * 512 + k, isbf);
      } else {
        v[j] = (qd == 0) ? (short)ldbf(Wih_e, (size_t)row * 8 + j, isbf) : (short)0;
      }
    }
    short* dst = AEnc + ((size_t)bidp * 64 + lane) * 8;
#pragma unroll
    for (int j = 0; j < 8; ++j) dst[j] = v[j];
  } else {
    bidp -= 2176;
    const int hb = bidp / 64, rem = bidp % 64, t = rem / 16, kb = rem % 16;
    const int row = t * 512 + hb * 16 + m;
    short* dst = ADec + ((size_t)bidp * 64 + lane) * 8;
#pragma unroll
    for (int j = 0; j < 8; ++j) {
      int k = kb * 32 + qd * 8 + j;
      dst[j] = (short)ldbf(Whh_d, (size_t)row * 512 + k, isbf);
    }
  }
}

// ---------- prepack encoder x B-frags: XF[t][col][8] bf16 ----------
__global__ void k_prep_xf(const void* __restrict__ src, unsigned short* __restrict__ XF,
                          const int* __restrict__ flag) {
  const int isbf = *flag;
  int idx = blockIdx.x * 256 + threadIdx.x;        // < 524288
  int t = idx >> 10, rem = idx & 1023, col = rem >> 3, i = rem & 7;
  XF[idx] = ldbf(src, ((size_t)col * 512 + t) * 8 + i, isbf);
}

// ---------- small prep ----------
__global__ void k_prep_small(const void* __restrict__ bih_e, const void* __restrict__ bhh_e,
                             const void* __restrict__ bih_d, const void* __restrict__ bhh_d,
                             const void* __restrict__ Wih_d, const void* __restrict__ Wp,
                             const void* __restrict__ bp, const void* __restrict__ Wfc,
                             const void* __restrict__ bfc,
                             float* __restrict__ bE, float* __restrict__ uD,
                             float* __restrict__ bD, float* __restrict__ WfcF,
                             unsigned* __restrict__ arr, const int* __restrict__ flag) {
  const int isbf = *flag;
  const int b = blockIdx.x;
  if (b < 8) {
    int g = b * 256 + threadIdx.x;
    bE[g] = ldf(bih_e, g, isbf) + ldf(bhh_e, g, isbf);
    float u = 0.f, w0 = 0.f;
    for (int i = 0; i < 8; ++i) {
      float wv = ldf(Wih_d, (size_t)g * 8 + i, isbf);
      u  += wv * ldf(Wp, i, isbf);
      w0 += wv * ldf(bp, i, isbf);
    }
    uD[g] = u;
    bD[g] = ldf(bih_d, g, isbf) + ldf(bhh_d, g, isbf) + w0;
  } else if (b == 8) {
    for (int k = threadIdx.x; k < 513; k += 256)
      WfcF[k] = (k < 512) ? ldf(Wfc, k, isbf) : ldf(bfc, 0, isbf);
  } else {
    for (int i = threadIdx.x; i < 256 * FS; i += 256) arr[i] = 0u;  // 256 wave-flags
  }
}

// ---------- math ----------
__device__ __forceinline__ float sigm(float x) { return 1.0f / (1.0f + __expf(-x)); }
__device__ __forceinline__ float tanh_(float x) {
  float ax = fabsf(x);
  float e = __expf(-2.0f * ax);
  float t = (1.0f - e) / (1.0f + e);
  return copysignf(t, x);
}

// ---------- main persistent recurrent kernel ----------
__global__ __launch_bounds__(256, 1) void k_rnn(
    const short* __restrict__ AEnc, const short* __restrict__ ADec,
    const unsigned short* __restrict__ XF,
    const float* __restrict__ bE, const float* __restrict__ uD,
    const float* __restrict__ bD, const float* __restrict__ WfcF,
    float* __restrict__ hA, float* __restrict__ hB,
    void* __restrict__ outp, const int* __restrict__ flag,
    unsigned* __restrict__ arr, const void* __restrict__ src) {
  const int bid  = (int)blockIdx.x;       // 64 blocks
  const int hb   = bid >> 1;              // produces h rows hb*16 .. +16
  const int half = bid & 1;
  const int tid  = (int)threadIdx.x;
  const int lane = tid & 63;
  const int w    = __builtin_amdgcn_readfirstlane(tid >> 6);  // col-tile 0..3
  const int n    = lane & 15, q = lane >> 4;
  const int col  = half * 64 + w * 16 + n;

  __shared__ short AeL[4 * 17 * 512];     // 69632 B
  __shared__ short AdL[4 * 16 * 512];     // 65536 B
  __shared__ float WfcL[520];
  __shared__ float bEL[64], uDL[64], bDL[64];

  // ---- one-time staging ----
  {
    const float4* s1 = (const float4*)(AEnc + (size_t)hb * 34816);
    float4* d1 = (float4*)AeL;
    for (int i = tid; i < 4352; i += 256) d1[i] = s1[i];
    const float4* s2 = (const float4*)(ADec + (size_t)hb * 32768);
    float4* d2 = (float4*)AdL;
    for (int i = tid; i < 4096; i += 256) d2[i] = s2[i];
    for (int k = tid; k < 513; k += 256) WfcL[k] = WfcF[k];
    if (tid < 64) {
      int t = tid >> 4, m = tid & 15;
      int g = t * 512 + hb * 16 + m;
      bEL[tid] = bE[g]; uDL[tid] = uD[g]; bDL[tid] = bD[g];
    }
  }
  const int isbf = *flag;
  // wave flag id = ((hb*2+half)*4 + w); producers: all hb', same (half,w)
  const unsigned* pf = arr + (size_t)((((lane & 31) * 2 + half) * 4 + w) * FS);
  unsigned* myflag = arr + (size_t)(((hb * 2 + half) * 4 + w) * FS);
  __syncthreads();   // LDS staging visible; last block-level sync

  const size_t lbase = (size_t)col * 512 + q * 8;            // consumer float idx
  const size_t sbase = (size_t)col * 512 + hb * 16 + q * 4;  // producer float idx
  float cst[4] = {0.f, 0.f, 0.f, 0.f};

#define WAIT(nn)                                                              \
  do {                                                                        \
    unsigned _n = (unsigned)(nn);                                             \
    while (!__all((int)(ld_flag(pf) >= _n))) __builtin_amdgcn_s_sleep(1);     \
    asm volatile("" ::: "memory");                                            \
  } while (0)

  // ================= encoder: 512 steps =================
  for (int t = 0; t < 512; ++t) {
    const float* bufR = (t & 1) ? hB : hA;       // h_t
    float* bufW = (t & 1) ? hA : hB;             // h_{t+1}
    f32x4 acc[4] = {{0.f,0.f,0.f,0.f},{0.f,0.f,0.f,0.f},{0.f,0.f,0.f,0.f},{0.f,0.f,0.f,0.f}};
    short8 xb = short8{0,0,0,0,0,0,0,0};
    if (q == 0) xb = *(const short8*)((const short*)XF + ((size_t)t * 128 + col) * 8);

    if (t > 0) {
      WAIT(t);
      f32x4 hv[32];
      load_h32(bufR + lbase, hv);                // 32 b128 loads + drain, in-asm
#pragma unroll
      for (int kb = 0; kb < 16; ++kb) {
        union { unsigned short us[8]; short8 v; } B0, B1, B2;
#pragma unroll
        for (int j = 0; j < 8; ++j) {            // exact 3-way RNE split (r7 values)
          float x = (j < 4) ? hv[2 * kb][j] : hv[2 * kb + 1][j - 4];
          unsigned short a = f2bf(x);
          float r1 = x - bf2f((short)a);
          unsigned short bq = f2bf(r1);
          float r2 = r1 - bf2f((short)bq);
          B0.us[j] = a; B1.us[j] = bq; B2.us[j] = f2bf(r2);
        }
#pragma unroll
        for (int tt = 0; tt < 4; ++tt) {
          short8 a = *(const short8*)(AeL + ((size_t)(tt * 17 + kb) * 64 + lane) * 8);
          acc[tt] = __builtin_amdgcn_mfma_f32_16x16x32_bf16(a, B0.v, acc[tt], 0, 0, 0);
          acc[tt] = __builtin_amdgcn_mfma_f32_16x16x32_bf16(a, B1.v, acc[tt], 0, 0, 0);
          acc[tt] = __builtin_amdgcn_mfma_f32_16x16x32_bf16(a, B2.v, acc[tt], 0, 0, 0);
        }
      }
    }
#pragma unroll
    for (int tt = 0; tt < 4; ++tt) {   // x-term K-block (last: r7 order)
      short8 a = *(const short8*)(AeL + ((size_t)(tt * 17 + 16) * 64 + lane) * 8);
      acc[tt] = __builtin_amdgcn_mfma_f32_16x16x32_bf16(a, xb, acc[tt], 0, 0, 0);
    }
    f32x4 hw;
#pragma unroll
    for (int r = 0; r < 4; ++r) {
      int m = q * 4 + r;
      float gi = acc[0][r] + bEL[m];
      float gf = acc[1][r] + bEL[16 + m];
      float gg = acc[2][r] + bEL[32 + m];
      float go = acc[3][r] + bEL[48 + m];
      cst[r] = sigm(gf) * cst[r] + sigm(gi) * tanh_(gg);
      hw[r] = sigm(go) * tanh_(cst[r]);
    }
    st_cx4(bufW + sbase, hw);
    vm_drain();
    if (lane == 0) st_flag(myflag, (unsigned)(t + 1));
  }

  // ================= decoder: 96 steps =================
  for (int d = 0; d < 96; ++d) {
    const int nn = 512 + d;
    const float* bufR = (nn & 1) ? hB : hA;
    float* bufW = (nn & 1) ? hA : hB;
    f32x4 acc[4] = {{0.f,0.f,0.f,0.f},{0.f,0.f,0.f,0.f},{0.f,0.f,0.f,0.f},{0.f,0.f,0.f,0.f}};
    float pd = 0.f;
    WAIT(nn);
    f32x4 hv[32];
    load_h32(bufR + lbase, hv);
#pragma unroll
    for (int kb = 0; kb < 16; ++kb) {
      union { unsigned short us[8]; short8 v; } B0, B1, B2;
#pragma unroll
      for (int j = 0; j < 8; ++j) {
        float x = (j < 4) ? hv[2 * kb][j] : hv[2 * kb + 1][j - 4];
        unsigned short a = f2bf(x);
        float r1 = x - bf2f((short)a);
        unsigned short bq = f2bf(r1);
        float r2 = r1 - bf2f((short)bq);
        B0.us[j] = a; B1.us[j] = bq; B2.us[j] = f2bf(r2);
        pd += WfcL[kb * 32 + q * 8 + j] *
              (bf2f((short)B0.us[j]) + bf2f((short)B1.us[j]) + bf2f((short)B2.us[j]));
      }
#pragma unroll
      for (int tt = 0; tt < 4; ++tt) {
        short8 a = *(const short8*)(AdL + ((size_t)(tt * 16 + kb) * 64 + lane) * 8);
        acc[tt] = __builtin_amdgcn_mfma_f32_16x16x32_bf16(a, B0.v, acc[tt], 0, 0, 0);
        acc[tt] = __builtin_amdgcn_mfma_f32_16x16x32_bf16(a, B1.v, acc[tt], 0, 0, 0);
        acc[tt] = __builtin_amdgcn_mfma_f32_16x16x32_bf16(a, B2.v, acc[tt], 0, 0, 0);
      }
    }
    pd += __shfl_xor(pd, 16);
    pd += __shfl_xor(pd, 32);
    float pr = sigm(pd + WfcL[512]);             // pred from h_{512+d} = pred_{d-1}
    float xin = (d == 0) ? ldf(src, (size_t)col * 4096 + 4088, isbf) : pr;
    if (hb == 0 && q == 0 && d > 0) {
      int oi = col * 96 + (d - 1);
      if (isbf) ((unsigned short*)outp)[oi] = f2bf(pr);
      else      ((float*)outp)[oi] = pr;
    }
    f32x4 hw;
#pragma unroll
    for (int r = 0; r < 4; ++r) {
      int m = q * 4 + r;
      float gi = acc[0][r] + xin * uDL[m]      + bDL[m];
      float gf = acc[1][r] + xin * uDL[16 + m] + bDL[16 + m];
      float gg = acc[2][r] + xin * uDL[32 + m] + bDL[32 + m];
      float go = acc[3][r] + xin * uDL[48 + m] + bDL[48 + m];
      cst[r] = sigm(gf) * cst[r] + sigm(gi) * tanh_(gg);
      hw[r] = sigm(go) * tanh_(cst[r]);
    }
    st_cx4(bufW + sbase, hw);
    vm_drain();
    if (lane == 0) st_flag(myflag, (unsigned)(nn + 1));
  }

  // ================= epilogue: pred_95 from h_608 (in hA) =================
  if (hb == 0) {
    WAIT(608u);
    f32x4 hv[32];
    load_h32(hA + lbase, hv);
    float pd = 0.f;
#pragma unroll
    for (int kb = 0; kb < 16; ++kb)
#pragma unroll
      for (int j = 0; j < 8; ++j) {
        float x = (j < 4) ? hv[2 * kb][j] : hv[2 * kb + 1][j - 4];
        unsigned short a = f2bf(x);
        float r1 = x - bf2f((short)a);
        unsigned short bq = f2bf(r1);
        float r2 = r1 - bf2f((short)bq);
        pd += WfcL[kb * 32 + q * 8 + j] *
              (bf2f((short)a) + bf2f((short)bq) + bf2f((short)f2bf(r2)));
      }
    pd += __shfl_xor(pd, 16);
    pd += __shfl_xor(pd, 32);
    if (q == 0) {
      float pr = sigm(pd + WfcL[512]);
      int oi = col * 96 + 95;
      if (isbf) ((unsigned short*)outp)[oi] = f2bf(pr);
      else      ((float*)outp)[oi] = pr;
    }
  }
#undef WAIT
}

// ---------- host ----------
extern "C" void kernel_launch(void* const* d_in, const int* in_sizes, int n_in,
                              void* d_out, int out_size, void* d_ws, size_t ws_size,
                              hipStream_t stream) {
  (void)in_sizes; (void)n_in; (void)out_size; (void)ws_size;
  char* ws = (char*)d_ws;
  int* flag = (int*)ws;                                   // @0
  unsigned* arr = (unsigned*)(ws + 128);                  // 256 wave-flags x 128 B = 32768
  size_t off = 128 + 32768 + 128;                         // 33024
  short* AEnc = (short*)(ws + off);           off += (size_t)2176 * 512 * 2;  // 2228224
  short* ADec = (short*)(ws + off);           off += (size_t)2048 * 512 * 2;  // 2097152
  unsigned short* XF = (unsigned short*)(ws + off); off += (size_t)524288 * 2; // 1048576
  float* hA   = (float*)(ws + off); off += 262144;        // 128 cols x 512 k fp32
  float* hB   = (float*)(ws + off); off += 262144;
  float* bE   = (float*)(ws + off); off += 8192;
  float* uD   = (float*)(ws + off); off += 8192;
  float* bD   = (float*)(ws + off); off += 8192;
  float* WfcF = (float*)(ws + off); off += 2080;

  // inputs: 0 src, 1 Wih_e, 2 Whh_e, 3 bih_e, 4 bhh_e, 5 Wih_d, 6 Whh_d,
  //         7 bih_d, 8 bhh_d, 9 Wp, 10 bp, 11 Wfc, 12 bfc
  k_probe<<<dim3(1), dim3(256), 0, stream>>>((const unsigned int*)d_in[0], flag);
  k_prep_frags<<<dim3(4224), dim3(64), 0, stream>>>(
      d_in[2], d_in[6], d_in[1], AEnc, ADec, flag);
  k_prep_xf<<<dim3(2048), dim3(256), 0, stream>>>(d_in[0], XF, flag);
  k_prep_small<<<dim3(10), dim3(256), 0, stream>>>(
      d_in[3], d_in[4], d_in[7], d_in[8], d_in[5], d_in[9], d_in[10],
      d_in[11], d_in[12], bE, uD, bD, WfcF, arr, flag);
  k_rnn<<<dim3(64), dim3(256), 0, stream>>>(
      AEnc, ADec, XF, bE, uD, bD, WfcF, hA, hB, d_out, flag, arr, d_in[0]);
}